// Round 11
// baseline (1433.677 us; speedup 1.0000x reference)
//
#include <hip/hip_runtime.h>
#include <math.h>

#define N_TOK 131072
#define D 256
#define K_CODES 1024
#define SMALL_CAP 90112
#define OVF_CAP 16384

typedef short bf16x8 __attribute__((ext_vector_type(8)));
typedef float f32x4 __attribute__((ext_vector_type(4)));

__device__ __forceinline__ unsigned short f2bf(float f) {
  unsigned x = __float_as_uint(f);
  unsigned r = x + 0x7fffu + ((x >> 16) & 1u);
  return (unsigned short)(r >> 16);
}
__device__ __forceinline__ float bf2f(unsigned short u) {
  return __uint_as_float(((unsigned)u) << 16);
}

// ---------------------------------------------------------------- kernel 1
// fp64 code norms -> inv_nc64 (exact anchor, VALIDATED r8); bf16 cbb for MFMA
__global__ __launch_bounds__(256) void norm_cb_kernel(
    const float* __restrict__ cb, double* __restrict__ inv_nc64,
    unsigned short* __restrict__ cbb) {
  const int c = blockIdx.x;
  const int d = threadIdx.x;
  const float v = cb[(size_t)c * D + d];
  double ssd = (double)v * (double)v;
#pragma unroll
  for (int o = 32; o; o >>= 1) ssd += __shfl_down(ssd, o, 64);
  __shared__ double red[4];
  if ((d & 63) == 0) red[d >> 6] = ssd;
  __syncthreads();
  const double tot = red[0] + red[1] + red[2] + red[3];
  const double inv = 1.0 / fmax(sqrt(tot), 1e-12);
  if (d == 0) inv_nc64[c] = inv;
  cbb[(size_t)c * D + d] = f2bf((float)((double)v * inv));
}

// ---------------------------------------------------------------- kernel 2
// bf16 MFMA sims (VALIDATED math; r11: 16 slices of 512 codes x 32 k ->
// LDS 66KB -> 2 blocks/CU). acc values bit-identical to r10.
__global__ __launch_bounds__(512, 4) void vq_mfma_kernel(
    const float* __restrict__ z, const char* __restrict__ cbb,
    float* __restrict__ dw, float* __restrict__ out_codes,
    unsigned long long* __restrict__ small_list, int* __restrict__ small_cnt,
    int* __restrict__ ovf_list, int* __restrict__ ovf_cnt) {
  __shared__ __align__(16) char S[66048];  // [0,32K) z bf16; [32K,64K) cb slice
  __shared__ float norms[64];
  __shared__ int lds_codes[64];
  // alias region inside cb buffer (valid after K loop)
  int* cand = (int*)(S + 32768);             // 64 tok x 8 waves x 3 ints
  int* clist = (int*)(S + 32768 + 6144);     // 64 tok x 10 ints
  float* thrs = (float*)(S + 32768 + 8704);  // 64 floats
  int* ccnt = (int*)(S + 32768 + 8960);      // 64 ints

  const int tid = threadIdx.x;
  const int wv = tid >> 6;
  const int lane = tid & 63;
  const int t0b = blockIdx.x * 64;

  // ---- prologue: stage z (fp32->bf16, swizzled) + norms; cb slice 0
  {
    const int tok = tid >> 3, sub = tid & 7;
    const float* zrow = z + (size_t)(t0b + tok) * D;
    float ss = 0.f;
#pragma unroll
    for (int i = 0; i < 4; ++i) {
      const int ku = sub + 8 * i;
      const float4 a = *(const float4*)(zrow + ku * 8);
      const float4 b = *(const float4*)(zrow + ku * 8 + 4);
      ss += a.x * a.x + a.y * a.y + a.z * a.z + a.w * a.w;
      ss += b.x * b.x + b.y * b.y + b.z * b.z + b.w * b.w;
      union { unsigned short h[8]; int4 v; } u;
      u.h[0] = f2bf(a.x); u.h[1] = f2bf(a.y); u.h[2] = f2bf(a.z); u.h[3] = f2bf(a.w);
      u.h[4] = f2bf(b.x); u.h[5] = f2bf(b.y); u.h[6] = f2bf(b.z); u.h[7] = f2bf(b.w);
      const int phys = (tok << 5) + (ku ^ (tok & 15));
      *(int4*)(S + ((size_t)phys << 4)) = u.v;
    }
    ss += __shfl_xor(ss, 1, 64);
    ss += __shfl_xor(ss, 2, 64);
    ss += __shfl_xor(ss, 4, 64);
    if (sub == 0) norms[tok] = sqrtf(ss);
    // cb slice 0 (codes [0,512), k [0,32)) -> buf
#pragma unroll
    for (int i = 0; i < 4; ++i) {
      const int v = tid + (i << 9);
      const int code = v >> 2, kk = v & 3;
      const int4 g = *(const int4*)(cbb + (size_t)code * 512 + (kk << 4));
      *(int4*)(S + 32768 + (code << 6) + ((kk ^ (code & 3)) << 4)) = g;
    }
  }
  __syncthreads();

  f32x4 acc[4][8];
#pragma unroll
  for (int t = 0; t < 4; ++t)
#pragma unroll
    for (int c = 0; c < 8; ++c) acc[t][c] = (f32x4){0.f, 0.f, 0.f, 0.f};

  const int tk = lane & 15;
  const int kg = lane >> 4;

  // ---- K loop: 16 slices; slice s = codes-half (s&1), k-slice (s>>1)
  for (int s = 0; s < 16; ++s) {
    const int h = s & 1, ks = s >> 1;
    bf16x8 zf[4];
#pragma unroll
    for (int tt = 0; tt < 4; ++tt) {
      const int tok = tt * 16 + tk;
      const int ku = (ks << 2) + kg;
      zf[tt] = *(const bf16x8*)(S + (((tok << 5) + (ku ^ (tok & 15))) << 4));
    }
    int4 g0, g1, g2, g3;
    if (s < 15) {
      const char* gp = cbb + ((size_t)((s + 1) & 1) << 18) + (((s + 1) >> 1) << 6);
#define LOADG(I, R)                                                     \
  { const int v = tid + (I << 9); const int code = v >> 2, kk = v & 3;  \
    R = *(const int4*)(gp + (size_t)code * 512 + (kk << 4)); }
      LOADG(0, g0) LOADG(1, g1) LOADG(2, g2) LOADG(3, g3)
#undef LOADG
    }
    const int hq = h * 4;
#pragma unroll
    for (int ct = 0; ct < 4; ++ct) {
      const int code = (wv << 6) + (ct << 4) + tk;
      const bf16x8 cf =
          *(const bf16x8*)(S + 32768 + (code << 6) + ((kg ^ (code & 3)) << 4));
      acc[0][hq + ct] = __builtin_amdgcn_mfma_f32_16x16x32_bf16(cf, zf[0], acc[0][hq + ct], 0, 0, 0);
      acc[1][hq + ct] = __builtin_amdgcn_mfma_f32_16x16x32_bf16(cf, zf[1], acc[1][hq + ct], 0, 0, 0);
      acc[2][hq + ct] = __builtin_amdgcn_mfma_f32_16x16x32_bf16(cf, zf[2], acc[2][hq + ct], 0, 0, 0);
      acc[3][hq + ct] = __builtin_amdgcn_mfma_f32_16x16x32_bf16(cf, zf[3], acc[3][hq + ct], 0, 0, 0);
    }
    __syncthreads();  // all reads of current slice done
    if (s < 15) {
#define STOREG(I, R)                                                    \
  { const int v = tid + (I << 9); const int code = v >> 2, kk = v & 3;  \
    *(int4*)(S + 32768 + (code << 6) + ((kk ^ (code & 3)) << 4)) = R; }
      STOREG(0, g0) STOREG(1, g1) STOREG(2, g2) STOREG(3, g3)
#undef STOREG
    }
    __syncthreads();  // next slice visible
  }

  // ---- per-wave top-2 (index for top-1) per token -> cand area
  // acc[tt][j]: code = (j>>2)*512 + wv*64 + (j&3)*16 + kg*4 + r
#pragma unroll
  for (int tt = 0; tt < 4; ++tt) {
    float t1 = -3.0e38f, t2 = -3.0e38f;
    int i1 = 0;
#pragma unroll
    for (int j = 0; j < 8; ++j)
#pragma unroll
      for (int r = 0; r < 4; ++r) {
        const float v = acc[tt][j][r];
        const int k = ((j >> 2) << 9) + (wv << 6) + ((j & 3) << 4) + (kg << 2) + r;
        if (v > t1) { t2 = t1; t1 = v; i1 = k; }
        else if (v > t2) t2 = v;
      }
#pragma unroll
    for (int off = 16; off <= 32; off <<= 1) {
      const float o1 = __shfl_xor(t1, off, 64);
      const int oi1 = __shfl_xor(i1, off, 64);
      const float o2 = __shfl_xor(t2, off, 64);
      const bool take = (o1 > t1) || (o1 == t1 && oi1 < i1);
      const float lo = take ? t1 : o1;
      t1 = take ? o1 : t1;
      i1 = take ? oi1 : i1;
      t2 = fmaxf(fmaxf(t2, o2), lo);
    }
    if (lane < 16) {
      int* p = cand + ((tt * 16 + lane) * 8 + wv) * 3;
      p[0] = __float_as_int(t1);
      p[1] = i1;
      p[2] = __float_as_int(t2);
    }
  }
  __syncthreads();

  // ---- resolver pass 1: thr + certified decision
  if (tid < 64) {
    const float nrm = norms[tid];
    const float margin = 0.016f * nrm + 1.5e-3f;  // 2*(2^-8+2^-8)*||z|| + slack
    const int* base = cand + tid * 24;
    float v1 = -3.0e38f, v2 = -3.0e38f;
    int j1 = 0x7fffffff;
#pragma unroll
    for (int w = 0; w < 8; ++w) {
      const float a1 = __int_as_float(base[w * 3]);
      const int ai = base[w * 3 + 1];
      const float a2 = __int_as_float(base[w * 3 + 2]);
      const bool take = (a1 > v1) || (a1 == v1 && ai < j1);
      const float lo = take ? v1 : a1;
      v1 = take ? a1 : v1;
      j1 = take ? ai : j1;
      v2 = fmaxf(fmaxf(v2, a2), lo);
    }
    const float thr = v1 - margin;
    const bool cert = (v2 < thr);
    thrs[tid] = cert ? 3.0e38f : thr;
    ccnt[tid] = 0;
    lds_codes[tid] = cert ? j1 : -1;
    out_codes[t0b + tid] = (float)j1;  // final if certified, else provisional
  }
  __syncthreads();

  // ---- collect pass: append every code with S_bf >= thr (flagged tokens)
#pragma unroll
  for (int tt = 0; tt < 4; ++tt) {
    const int tok = tt * 16 + tk;
    const float thr_t = thrs[tok];
#pragma unroll
    for (int j = 0; j < 8; ++j)
#pragma unroll
      for (int r = 0; r < 4; ++r) {
        if (acc[tt][j][r] >= thr_t) {
          const int pos = atomicAdd(&ccnt[tok], 1);
          if (pos < 10)
            clist[tok * 10 + pos] =
                ((j >> 2) << 9) + (wv << 6) + ((j & 3) << 4) + (kg << 2) + r;
        }
      }
  }
  __syncthreads();

  // ---- resolver pass 2: route flagged token to small list or overflow list
  if (tid < 64) {
    const int cnt = ccnt[tid];
    if (cnt > 0) {
      bool to_ovf = (cnt > 10);
      if (!to_ovf) {
        const int pos = atomicAdd(small_cnt, 1);
        if (pos < SMALL_CAP) {
          unsigned long long w0 =
              (unsigned long long)(t0b + tid) | ((unsigned long long)cnt << 17);
          unsigned long long w1 = 0;
          for (int j = 0; j < cnt && j < 4; ++j)
            w0 |= ((unsigned long long)(clist[tid * 10 + j] & 1023)) << (21 + 10 * j);
          for (int j = 4; j < cnt; ++j)
            w1 |= ((unsigned long long)(clist[tid * 10 + j] & 1023)) << (10 * (j - 4));
          small_list[2 * pos] = w0;
          small_list[2 * pos + 1] = w1;
        } else {
          to_ovf = true;
        }
      }
      if (to_ovf) {
        const int p2 = atomicAdd(ovf_cnt, 1);
        if (p2 < OVF_CAP) ovf_list[p2] = t0b + tid;
      }
    }
  }
  __syncthreads();

  // ---- dw atomics for certified tokens (z_n from LDS bf16)
  {
    const int tok = tid >> 3, sub = tid & 7;
    const int code = lds_codes[tok];
    if (code >= 0) {
      const float inv = 1.0f / fmaxf(norms[tok], 1e-12f);
      float* drow = dw + (size_t)code * D;
#pragma unroll
      for (int i = 0; i < 4; ++i) {
        const int ku = sub + 8 * i;
        const int phys = (tok << 5) + (ku ^ (tok & 15));
        union { unsigned short h[8]; int4 v; } u;
        u.v = *(const int4*)(S + ((size_t)phys << 4));
#pragma unroll
        for (int j = 0; j < 8; ++j)
          unsafeAtomicAdd(drow + ku * 8 + j, bf2f(u.h[j]) * inv);
      }
    }
  }
}

// ---------------------------------------------------------------- kernel 3
// small recheck (VALIDATED r8 math): one wave per flagged entry (cnt<=10)
__global__ __launch_bounds__(256) void recheck_small_kernel(
    const float* __restrict__ z, const float* __restrict__ cb,
    const double* __restrict__ inv_nc64,
    const unsigned long long* __restrict__ small_list,
    const int* __restrict__ small_cnt, float* __restrict__ out_codes,
    float* __restrict__ dw) {
  int n = *small_cnt;
  if (n > SMALL_CAP) n = SMALL_CAP;
  const int lane = threadIdx.x & 63;
  const int wid = (blockIdx.x * blockDim.x + threadIdx.x) >> 6;
  const int nw = (gridDim.x * blockDim.x) >> 6;
  for (int i = wid; i < n; i += nw) {
    const unsigned long long w0 = small_list[2 * i];
    const unsigned long long w1 = small_list[2 * i + 1];
    const int t = (int)(w0 & 0x1ffff);
    const int cnt = (int)((w0 >> 17) & 15);
    const float4 zr = *(const float4*)(z + (size_t)t * D + lane * 4);
    const double z0 = zr.x, z1 = zr.y, z2 = zr.z, z3 = zr.w;
    double ssd = z0 * z0 + z1 * z1 + z2 * z2 + z3 * z3;
#pragma unroll
    for (int o = 32; o; o >>= 1) ssd += __shfl_xor(ssd, o, 64);
    double best = -1.0e300;
    int bi = 0x7fffffff;
    for (int j = 0; j < cnt; ++j) {
      const int c = (j < 4) ? (int)((w0 >> (21 + 10 * j)) & 1023)
                            : (int)((w1 >> (10 * (j - 4))) & 1023);
      const float4 cr = *(const float4*)(cb + (size_t)c * D + lane * 4);
      double p = z0 * (double)cr.x + z1 * (double)cr.y +
                 z2 * (double)cr.z + z3 * (double)cr.w;
#pragma unroll
      for (int o = 32; o; o >>= 1) p += __shfl_xor(p, o, 64);
      p *= inv_nc64[c];
      if (p > best || (p == best && c < bi)) { best = p; bi = c; }
    }
    if (lane == 0) out_codes[t] = (float)bi;
    const float inv = 1.0f / fmaxf((float)sqrt(ssd), 1e-12f);
    float* drow = dw + (size_t)bi * D + lane * 4;
    unsafeAtomicAdd(drow + 0, zr.x * inv);
    unsafeAtomicAdd(drow + 1, zr.y * inv);
    unsafeAtomicAdd(drow + 2, zr.z * inv);
    unsafeAtomicAdd(drow + 3, zr.w * inv);
  }
}

// ---------------------------------------------------------------- kernel 4
// overflow full scan: one 256-thread block per token, 4 codes per thread
__global__ __launch_bounds__(256) void fullscan_kernel(
    const float* __restrict__ z, const float* __restrict__ cb,
    const double* __restrict__ inv_nc64, const int* __restrict__ ovf_list,
    const int* __restrict__ ovf_cnt, float* __restrict__ out_codes,
    float* __restrict__ dw) {
  __shared__ float zs[256];
  __shared__ double bv[256];
  __shared__ int bis[256];
  int n = *ovf_cnt;
  if (n > OVF_CAP) n = OVF_CAP;
  for (int i = blockIdx.x; i < n; i += gridDim.x) {
    const int t = ovf_list[i];
    zs[threadIdx.x] = z[(size_t)t * D + threadIdx.x];
    __syncthreads();
    double best = -1.0e300;
    int bidx = 0x7fffffff;
#pragma unroll
    for (int cc = 0; cc < 4; ++cc) {
      const int c = threadIdx.x + (cc << 8);
      const float* crow = cb + (size_t)c * D;
      double p = 0.0;
#pragma unroll 8
      for (int k = 0; k < D; ++k) p += (double)zs[k] * (double)crow[k];
      p *= inv_nc64[c];
      if (p > best || (p == best && c < bidx)) { best = p; bidx = c; }
    }
    bv[threadIdx.x] = best;
    bis[threadIdx.x] = bidx;
    __syncthreads();
    for (int s = 128; s; s >>= 1) {
      if (threadIdx.x < s) {
        const double ov = bv[threadIdx.x + s];
        const int oi = bis[threadIdx.x + s];
        if (ov > bv[threadIdx.x] ||
            (ov == bv[threadIdx.x] && oi < bis[threadIdx.x])) {
          bv[threadIdx.x] = ov;
          bis[threadIdx.x] = oi;
        }
      }
      __syncthreads();
    }
    const int code = bis[0];
    if (threadIdx.x == 0) out_codes[t] = (float)code;
    __syncthreads();
    bv[threadIdx.x] = (double)zs[threadIdx.x] * (double)zs[threadIdx.x];
    __syncthreads();
    for (int s = 128; s; s >>= 1) {
      if (threadIdx.x < s) bv[threadIdx.x] += bv[threadIdx.x + s];
      __syncthreads();
    }
    const float inv = 1.0f / fmaxf((float)sqrt(bv[0]), 1e-12f);
    unsafeAtomicAdd(dw + (size_t)code * D + threadIdx.x,
                    zs[threadIdx.x] * inv);
    __syncthreads();
  }
}

// ---------------------------------------------------------------- kernel 5
// embed = l2norm(0.97*ema_w + 0.03*dw), in place over dw
__global__ __launch_bounds__(256) void ema_embed_kernel(
    const float* __restrict__ ema_w, float* __restrict__ dwe) {
  const int c = blockIdx.x;
  const int d = threadIdx.x;
  const size_t idx = (size_t)c * D + d;
  const float w = 0.97f * ema_w[idx] + 0.03f * dwe[idx];
  float ss = w * w;
#pragma unroll
  for (int o = 32; o; o >>= 1) ss += __shfl_down(ss, o, 64);
  __shared__ float red[4];
  if ((d & 63) == 0) red[d >> 6] = ss;
  __syncthreads();
  const float tot = red[0] + red[1] + red[2] + red[3];
  dwe[idx] = w / fmaxf(sqrtf(tot), 1e-12f);
}

// ---------------------------------------------------------------- kernel 6
__global__ __launch_bounds__(256) void gather_loss_kernel(
    const float* __restrict__ z, const float* __restrict__ embed,
    const float* __restrict__ codesf, float* __restrict__ out0,
    double* __restrict__ loss) {
  const size_t u0 = (size_t)blockIdx.x * 4096 + threadIdx.x;
  float part = 0.f;
#pragma unroll 4
  for (int i = 0; i < 16; ++i) {
    const size_t u = u0 + (size_t)i * 256;
    const size_t t = u >> 6;
    const int k4 = (int)(u & 63);
    const int code = (int)codesf[t];
    const float4 e = *(const float4*)(embed + (size_t)code * D + 4 * k4);
    const float4 ze = *(const float4*)(z + t * D + 4 * k4);
    *(float4*)(out0 + t * D + 4 * k4) = e;
    const float dx = ze.x - e.x, dy = ze.y - e.y;
    const float dz = ze.z - e.z, dw4 = ze.w - e.w;
    part += dx * dx + dy * dy + dz * dz + dw4 * dw4;
  }
#pragma unroll
  for (int o = 32; o; o >>= 1) part += __shfl_down(part, o, 64);
  __shared__ float red[4];
  if ((threadIdx.x & 63) == 0) red[threadIdx.x >> 6] = part;
  __syncthreads();
  if (threadIdx.x == 0)
    unsafeAtomicAdd(loss, (double)(red[0] + red[1] + red[2] + red[3]));
}

// ---------------------------------------------------------------- kernel 7
__global__ void finalize_kernel(const double* __restrict__ loss,
                                float* __restrict__ out2) {
  out2[0] = (float)(0.25 * loss[0] / 33554432.0);
}

// ---------------------------------------------------------------- launcher
extern "C" void kernel_launch(void* const* d_in, const int* in_sizes, int n_in,
                              void* d_out, int out_size, void* d_ws, size_t ws_size,
                              hipStream_t stream) {
  const float* z = (const float*)d_in[0];
  const float* cb = (const float*)d_in[1];
  const float* ema_w = (const float*)d_in[3];

  float* out0 = (float*)d_out;
  float* out1 = out0 + (size_t)N_TOK * D;
  float* out2 = out1 + N_TOK;

  // ws layout, ~2.95 MB total (< proven-safe 3.15 MB)
  char* ws = (char*)d_ws;
  unsigned short* cbb = (unsigned short*)ws;                        // [0, 512K)
  float* dwe = (float*)(ws + 524288);                               // 1 MB
  unsigned long long* small_list = (unsigned long long*)(ws + 1572864);  // 1.375 MB
  int* ovf_list = (int*)(ws + 3014656);                             // 64 KB
  double* inv_nc64 = (double*)(ws + 3080192);                       // 8 KB
  int* small_cnt = (int*)(ws + 3088384);
  int* ovf_cnt = (int*)(ws + 3088388);
  double* loss = (double*)(ws + 3088448);

  hipMemsetAsync(dwe, 0, (size_t)K_CODES * D * sizeof(float), stream);
  hipMemsetAsync(ws + 3088384, 0, 128, stream);  // counters + loss

  norm_cb_kernel<<<K_CODES, 256, 0, stream>>>(cb, inv_nc64, cbb);
  vq_mfma_kernel<<<N_TOK / 64, 512, 0, stream>>>(
      z, (const char*)cbb, dwe, out1, small_list, small_cnt, ovf_list, ovf_cnt);
  recheck_small_kernel<<<2048, 256, 0, stream>>>(
      z, cb, inv_nc64, small_list, small_cnt, out1, dwe);
  fullscan_kernel<<<1024, 256, 0, stream>>>(
      z, cb, inv_nc64, ovf_list, ovf_cnt, out1, dwe);
  ema_embed_kernel<<<K_CODES, 256, 0, stream>>>(ema_w, dwe);
  gather_loss_kernel<<<2048, 256, 0, stream>>>(z, dwe, out1, out0, loss);
  finalize_kernel<<<1, 1, 0, stream>>>(loss, out2);
}

// Round 12
// 819.837 us; speedup vs baseline: 1.7487x; 1.7487x over previous
//
#include <hip/hip_runtime.h>
#include <math.h>

#define N_TOK 131072
#define D 256
#define K_CODES 1024
#define SMALL_CAP 90112
#define OVF_CAP 16384

typedef short bf16x8 __attribute__((ext_vector_type(8)));
typedef float f32x4 __attribute__((ext_vector_type(4)));

__device__ __forceinline__ unsigned short f2bf(float f) {
  unsigned x = __float_as_uint(f);
  unsigned r = x + 0x7fffu + ((x >> 16) & 1u);
  return (unsigned short)(r >> 16);
}
__device__ __forceinline__ float bf2f(unsigned short u) {
  return __uint_as_float(((unsigned)u) << 16);
}

// ---------------------------------------------------------------- kernel 1
// fp64 code norms -> inv_nc64 (exact anchor, VALIDATED r8); bf16 cbb for MFMA
__global__ __launch_bounds__(256) void norm_cb_kernel(
    const float* __restrict__ cb, double* __restrict__ inv_nc64,
    unsigned short* __restrict__ cbb) {
  const int c = blockIdx.x;
  const int d = threadIdx.x;
  const float v = cb[(size_t)c * D + d];
  double ssd = (double)v * (double)v;
#pragma unroll
  for (int o = 32; o; o >>= 1) ssd += __shfl_down(ssd, o, 64);
  __shared__ double red[4];
  if ((d & 63) == 0) red[d >> 6] = ssd;
  __syncthreads();
  const double tot = red[0] + red[1] + red[2] + red[3];
  const double inv = 1.0 / fmax(sqrt(tot), 1e-12);
  if (d == 0) inv_nc64[c] = inv;
  cbb[(size_t)c * D + d] = f2bf((float)((double)v * inv));
}

// ---------------------------------------------------------------- kernel 2
// bf16 MFMA sims (math VALIDATED r8-r11). r12: 32-token blocks -> acc 64
// regs/thread (no spill) + 16 slices of 512 codes x 32 k (cb 32KB).
__global__ __launch_bounds__(512, 4) void vq_mfma_kernel(
    const float* __restrict__ z, const char* __restrict__ cbb,
    float* __restrict__ dw, float* __restrict__ out_codes,
    unsigned long long* __restrict__ small_list, int* __restrict__ small_cnt,
    int* __restrict__ ovf_list, int* __restrict__ ovf_cnt) {
  __shared__ __align__(16) char S[49152];  // [0,16K) z bf16; [16K,48K) cb slice
  __shared__ float norms[32];
  __shared__ int lds_codes[32];
  // alias region inside cb buffer (valid after K loop)
  int* cand = (int*)(S + 16384);             // 32 tok x 8 waves x 3 ints
  int* clist = (int*)(S + 16384 + 3072);     // 32 tok x 10 ints
  float* thrs = (float*)(S + 16384 + 4352);  // 32 floats
  int* ccnt = (int*)(S + 16384 + 4480);      // 32 ints

  const int tid = threadIdx.x;
  const int wv = tid >> 6;
  const int lane = tid & 63;
  const int t0b = blockIdx.x * 32;

  // ---- prologue: stage z (fp32->bf16, swizzled) + norms; cb slice 0
  {
    const int tok = tid >> 4, sub = tid & 15;
    const float* zrow = z + (size_t)(t0b + tok) * D;
    float ss = 0.f;
#pragma unroll
    for (int i = 0; i < 2; ++i) {
      const int ku = sub + 16 * i;
      const float4 a = *(const float4*)(zrow + ku * 8);
      const float4 b = *(const float4*)(zrow + ku * 8 + 4);
      ss += a.x * a.x + a.y * a.y + a.z * a.z + a.w * a.w;
      ss += b.x * b.x + b.y * b.y + b.z * b.z + b.w * b.w;
      union { unsigned short h[8]; int4 v; } u;
      u.h[0] = f2bf(a.x); u.h[1] = f2bf(a.y); u.h[2] = f2bf(a.z); u.h[3] = f2bf(a.w);
      u.h[4] = f2bf(b.x); u.h[5] = f2bf(b.y); u.h[6] = f2bf(b.z); u.h[7] = f2bf(b.w);
      const int phys = (tok << 5) + (ku ^ (tok & 15));
      *(int4*)(S + ((size_t)phys << 4)) = u.v;
    }
    ss += __shfl_xor(ss, 1, 64);
    ss += __shfl_xor(ss, 2, 64);
    ss += __shfl_xor(ss, 4, 64);
    ss += __shfl_xor(ss, 8, 64);
    if (sub == 0) norms[tok] = sqrtf(ss);
    // cb slice 0 (codes [0,512), k [0,32)) -> buf
#pragma unroll
    for (int i = 0; i < 4; ++i) {
      const int v = tid + (i << 9);
      const int code = v >> 2, kk = v & 3;
      const int4 g = *(const int4*)(cbb + (size_t)code * 512 + (kk << 4));
      *(int4*)(S + 16384 + (code << 6) + ((kk ^ (code & 3)) << 4)) = g;
    }
  }
  __syncthreads();

  f32x4 acc[2][8];
#pragma unroll
  for (int t = 0; t < 2; ++t)
#pragma unroll
    for (int c = 0; c < 8; ++c) acc[t][c] = (f32x4){0.f, 0.f, 0.f, 0.f};

  const int tk = lane & 15;
  const int kg = lane >> 4;

  // ---- K loop: 16 slices; slice s = codes-half (s&1), k-slice (s>>1)
  for (int s = 0; s < 16; ++s) {
    const int h = s & 1, ks = s >> 1;
    bf16x8 zf[2];
#pragma unroll
    for (int tt = 0; tt < 2; ++tt) {
      const int tok = tt * 16 + tk;
      const int ku = (ks << 2) + kg;
      zf[tt] = *(const bf16x8*)(S + (((tok << 5) + (ku ^ (tok & 15))) << 4));
    }
    int4 g0, g1, g2, g3;
    if (s < 15) {
      const char* gp = cbb + ((size_t)((s + 1) & 1) << 18) + (((s + 1) >> 1) << 6);
#define LOADG(I, R)                                                     \
  { const int v = tid + (I << 9); const int code = v >> 2, kk = v & 3;  \
    R = *(const int4*)(gp + (size_t)code * 512 + (kk << 4)); }
      LOADG(0, g0) LOADG(1, g1) LOADG(2, g2) LOADG(3, g3)
#undef LOADG
    }
    const int hq = h * 4;
#pragma unroll
    for (int ct = 0; ct < 4; ++ct) {
      const int code = (wv << 6) + (ct << 4) + tk;
      const bf16x8 cf =
          *(const bf16x8*)(S + 16384 + (code << 6) + ((kg ^ (code & 3)) << 4));
      acc[0][hq + ct] = __builtin_amdgcn_mfma_f32_16x16x32_bf16(cf, zf[0], acc[0][hq + ct], 0, 0, 0);
      acc[1][hq + ct] = __builtin_amdgcn_mfma_f32_16x16x32_bf16(cf, zf[1], acc[1][hq + ct], 0, 0, 0);
    }
    __syncthreads();  // all reads of current slice done
    if (s < 15) {
#define STOREG(I, R)                                                    \
  { const int v = tid + (I << 9); const int code = v >> 2, kk = v & 3;  \
    *(int4*)(S + 16384 + (code << 6) + ((kk ^ (code & 3)) << 4)) = R; }
      STOREG(0, g0) STOREG(1, g1) STOREG(2, g2) STOREG(3, g3)
#undef STOREG
    }
    __syncthreads();  // next slice visible
  }

  // ---- per-wave top-2 (index for top-1) per token -> cand area
  // acc[tt][j]: code = (j>>2)*512 + wv*64 + (j&3)*16 + kg*4 + r
#pragma unroll
  for (int tt = 0; tt < 2; ++tt) {
    float t1 = -3.0e38f, t2 = -3.0e38f;
    int i1 = 0;
#pragma unroll
    for (int j = 0; j < 8; ++j)
#pragma unroll
      for (int r = 0; r < 4; ++r) {
        const float v = acc[tt][j][r];
        const int k = ((j >> 2) << 9) + (wv << 6) + ((j & 3) << 4) + (kg << 2) + r;
        if (v > t1) { t2 = t1; t1 = v; i1 = k; }
        else if (v > t2) t2 = v;
      }
#pragma unroll
    for (int off = 16; off <= 32; off <<= 1) {
      const float o1 = __shfl_xor(t1, off, 64);
      const int oi1 = __shfl_xor(i1, off, 64);
      const float o2 = __shfl_xor(t2, off, 64);
      const bool take = (o1 > t1) || (o1 == t1 && oi1 < i1);
      const float lo = take ? t1 : o1;
      t1 = take ? o1 : t1;
      i1 = take ? oi1 : i1;
      t2 = fmaxf(fmaxf(t2, o2), lo);
    }
    if (lane < 16) {
      int* p = cand + ((tt * 16 + lane) * 8 + wv) * 3;
      p[0] = __float_as_int(t1);
      p[1] = i1;
      p[2] = __float_as_int(t2);
    }
  }
  __syncthreads();

  // ---- resolver pass 1: thr + certified decision
  if (tid < 32) {
    const float nrm = norms[tid];
    const float margin = 0.016f * nrm + 1.5e-3f;  // 2*(2^-8+2^-8)*||z|| + slack
    const int* base = cand + tid * 24;
    float v1 = -3.0e38f, v2 = -3.0e38f;
    int j1 = 0x7fffffff;
#pragma unroll
    for (int w = 0; w < 8; ++w) {
      const float a1 = __int_as_float(base[w * 3]);
      const int ai = base[w * 3 + 1];
      const float a2 = __int_as_float(base[w * 3 + 2]);
      const bool take = (a1 > v1) || (a1 == v1 && ai < j1);
      const float lo = take ? v1 : a1;
      v1 = take ? a1 : v1;
      j1 = take ? ai : j1;
      v2 = fmaxf(fmaxf(v2, a2), lo);
    }
    const float thr = v1 - margin;
    const bool cert = (v2 < thr);
    thrs[tid] = cert ? 3.0e38f : thr;
    ccnt[tid] = 0;
    lds_codes[tid] = cert ? j1 : -1;
    out_codes[t0b + tid] = (float)j1;  // final if certified, else provisional
  }
  __syncthreads();

  // ---- collect pass: append every code with S_bf >= thr (flagged tokens)
#pragma unroll
  for (int tt = 0; tt < 2; ++tt) {
    const int tok = tt * 16 + tk;
    const float thr_t = thrs[tok];
#pragma unroll
    for (int j = 0; j < 8; ++j)
#pragma unroll
      for (int r = 0; r < 4; ++r) {
        if (acc[tt][j][r] >= thr_t) {
          const int pos = atomicAdd(&ccnt[tok], 1);
          if (pos < 10)
            clist[tok * 10 + pos] =
                ((j >> 2) << 9) + (wv << 6) + ((j & 3) << 4) + (kg << 2) + r;
        }
      }
  }
  __syncthreads();

  // ---- resolver pass 2: route flagged token to small list or overflow list
  if (tid < 32) {
    const int cnt = ccnt[tid];
    if (cnt > 0) {
      bool to_ovf = (cnt > 10);
      if (!to_ovf) {
        const int pos = atomicAdd(small_cnt, 1);
        if (pos < SMALL_CAP) {
          unsigned long long w0 =
              (unsigned long long)(t0b + tid) | ((unsigned long long)cnt << 17);
          unsigned long long w1 = 0;
          for (int j = 0; j < cnt && j < 4; ++j)
            w0 |= ((unsigned long long)(clist[tid * 10 + j] & 1023)) << (21 + 10 * j);
          for (int j = 4; j < cnt; ++j)
            w1 |= ((unsigned long long)(clist[tid * 10 + j] & 1023)) << (10 * (j - 4));
          small_list[2 * pos] = w0;
          small_list[2 * pos + 1] = w1;
        } else {
          to_ovf = true;
        }
      }
      if (to_ovf) {
        const int p2 = atomicAdd(ovf_cnt, 1);
        if (p2 < OVF_CAP) ovf_list[p2] = t0b + tid;
      }
    }
  }
  __syncthreads();

  // ---- dw atomics for certified tokens (z_n from LDS bf16)
  {
    const int tok = tid >> 4, sub = tid & 15;
    const int code = lds_codes[tok];
    if (code >= 0) {
      const float inv = 1.0f / fmaxf(norms[tok], 1e-12f);
      float* drow = dw + (size_t)code * D;
#pragma unroll
      for (int i = 0; i < 2; ++i) {
        const int ku = sub + 16 * i;
        const int phys = (tok << 5) + (ku ^ (tok & 15));
        union { unsigned short h[8]; int4 v; } u;
        u.v = *(const int4*)(S + ((size_t)phys << 4));
#pragma unroll
        for (int j = 0; j < 8; ++j)
          unsafeAtomicAdd(drow + ku * 8 + j, bf2f(u.h[j]) * inv);
      }
    }
  }
}

// ---------------------------------------------------------------- kernel 3
// small recheck (VALIDATED r8 math): one wave per flagged entry (cnt<=10)
__global__ __launch_bounds__(256) void recheck_small_kernel(
    const float* __restrict__ z, const float* __restrict__ cb,
    const double* __restrict__ inv_nc64,
    const unsigned long long* __restrict__ small_list,
    const int* __restrict__ small_cnt, float* __restrict__ out_codes,
    float* __restrict__ dw) {
  int n = *small_cnt;
  if (n > SMALL_CAP) n = SMALL_CAP;
  const int lane = threadIdx.x & 63;
  const int wid = (blockIdx.x * blockDim.x + threadIdx.x) >> 6;
  const int nw = (gridDim.x * blockDim.x) >> 6;
  for (int i = wid; i < n; i += nw) {
    const unsigned long long w0 = small_list[2 * i];
    const unsigned long long w1 = small_list[2 * i + 1];
    const int t = (int)(w0 & 0x1ffff);
    const int cnt = (int)((w0 >> 17) & 15);
    const float4 zr = *(const float4*)(z + (size_t)t * D + lane * 4);
    const double z0 = zr.x, z1 = zr.y, z2 = zr.z, z3 = zr.w;
    double ssd = z0 * z0 + z1 * z1 + z2 * z2 + z3 * z3;
#pragma unroll
    for (int o = 32; o; o >>= 1) ssd += __shfl_xor(ssd, o, 64);
    double best = -1.0e300;
    int bi = 0x7fffffff;
    for (int j = 0; j < cnt; ++j) {
      const int c = (j < 4) ? (int)((w0 >> (21 + 10 * j)) & 1023)
                            : (int)((w1 >> (10 * (j - 4))) & 1023);
      const float4 cr = *(const float4*)(cb + (size_t)c * D + lane * 4);
      double p = z0 * (double)cr.x + z1 * (double)cr.y +
                 z2 * (double)cr.z + z3 * (double)cr.w;
#pragma unroll
      for (int o = 32; o; o >>= 1) p += __shfl_xor(p, o, 64);
      p *= inv_nc64[c];
      if (p > best || (p == best && c < bi)) { best = p; bi = c; }
    }
    if (lane == 0) out_codes[t] = (float)bi;
    const float inv = 1.0f / fmaxf((float)sqrt(ssd), 1e-12f);
    float* drow = dw + (size_t)bi * D + lane * 4;
    unsafeAtomicAdd(drow + 0, zr.x * inv);
    unsafeAtomicAdd(drow + 1, zr.y * inv);
    unsafeAtomicAdd(drow + 2, zr.z * inv);
    unsafeAtomicAdd(drow + 3, zr.w * inv);
  }
}

// ---------------------------------------------------------------- kernel 4
// overflow full scan: one 256-thread block per token, 4 codes per thread
__global__ __launch_bounds__(256) void fullscan_kernel(
    const float* __restrict__ z, const float* __restrict__ cb,
    const double* __restrict__ inv_nc64, const int* __restrict__ ovf_list,
    const int* __restrict__ ovf_cnt, float* __restrict__ out_codes,
    float* __restrict__ dw) {
  __shared__ float zs[256];
  __shared__ double bv[256];
  __shared__ int bis[256];
  int n = *ovf_cnt;
  if (n > OVF_CAP) n = OVF_CAP;
  for (int i = blockIdx.x; i < n; i += gridDim.x) {
    const int t = ovf_list[i];
    zs[threadIdx.x] = z[(size_t)t * D + threadIdx.x];
    __syncthreads();
    double best = -1.0e300;
    int bidx = 0x7fffffff;
#pragma unroll
    for (int cc = 0; cc < 4; ++cc) {
      const int c = threadIdx.x + (cc << 8);
      const float* crow = cb + (size_t)c * D;
      double p = 0.0;
#pragma unroll 8
      for (int k = 0; k < D; ++k) p += (double)zs[k] * (double)crow[k];
      p *= inv_nc64[c];
      if (p > best || (p == best && c < bidx)) { best = p; bidx = c; }
    }
    bv[threadIdx.x] = best;
    bis[threadIdx.x] = bidx;
    __syncthreads();
    for (int s = 128; s; s >>= 1) {
      if (threadIdx.x < s) {
        const double ov = bv[threadIdx.x + s];
        const int oi = bis[threadIdx.x + s];
        if (ov > bv[threadIdx.x] ||
            (ov == bv[threadIdx.x] && oi < bis[threadIdx.x])) {
          bv[threadIdx.x] = ov;
          bis[threadIdx.x] = oi;
        }
      }
      __syncthreads();
    }
    const int code = bis[0];
    if (threadIdx.x == 0) out_codes[t] = (float)code;
    __syncthreads();
    bv[threadIdx.x] = (double)zs[threadIdx.x] * (double)zs[threadIdx.x];
    __syncthreads();
    for (int s = 128; s; s >>= 1) {
      if (threadIdx.x < s) bv[threadIdx.x] += bv[threadIdx.x + s];
      __syncthreads();
    }
    const float inv = 1.0f / fmaxf((float)sqrt(bv[0]), 1e-12f);
    unsafeAtomicAdd(dw + (size_t)code * D + threadIdx.x,
                    zs[threadIdx.x] * inv);
    __syncthreads();
  }
}

// ---------------------------------------------------------------- kernel 5
// embed = l2norm(0.97*ema_w + 0.03*dw), in place over dw
__global__ __launch_bounds__(256) void ema_embed_kernel(
    const float* __restrict__ ema_w, float* __restrict__ dwe) {
  const int c = blockIdx.x;
  const int d = threadIdx.x;
  const size_t idx = (size_t)c * D + d;
  const float w = 0.97f * ema_w[idx] + 0.03f * dwe[idx];
  float ss = w * w;
#pragma unroll
  for (int o = 32; o; o >>= 1) ss += __shfl_down(ss, o, 64);
  __shared__ float red[4];
  if ((d & 63) == 0) red[d >> 6] = ss;
  __syncthreads();
  const float tot = red[0] + red[1] + red[2] + red[3];
  dwe[idx] = w / fmaxf(sqrtf(tot), 1e-12f);
}

// ---------------------------------------------------------------- kernel 6
__global__ __launch_bounds__(256) void gather_loss_kernel(
    const float* __restrict__ z, const float* __restrict__ embed,
    const float* __restrict__ codesf, float* __restrict__ out0,
    double* __restrict__ loss) {
  const size_t u0 = (size_t)blockIdx.x * 4096 + threadIdx.x;
  float part = 0.f;
#pragma unroll 4
  for (int i = 0; i < 16; ++i) {
    const size_t u = u0 + (size_t)i * 256;
    const size_t t = u >> 6;
    const int k4 = (int)(u & 63);
    const int code = (int)codesf[t];
    const float4 e = *(const float4*)(embed + (size_t)code * D + 4 * k4);
    const float4 ze = *(const float4*)(z + t * D + 4 * k4);
    *(float4*)(out0 + t * D + 4 * k4) = e;
    const float dx = ze.x - e.x, dy = ze.y - e.y;
    const float dz = ze.z - e.z, dw4 = ze.w - e.w;
    part += dx * dx + dy * dy + dz * dz + dw4 * dw4;
  }
#pragma unroll
  for (int o = 32; o; o >>= 1) part += __shfl_down(part, o, 64);
  __shared__ float red[4];
  if ((threadIdx.x & 63) == 0) red[threadIdx.x >> 6] = part;
  __syncthreads();
  if (threadIdx.x == 0)
    unsafeAtomicAdd(loss, (double)(red[0] + red[1] + red[2] + red[3]));
}

// ---------------------------------------------------------------- kernel 7
__global__ void finalize_kernel(const double* __restrict__ loss,
                                float* __restrict__ out2) {
  out2[0] = (float)(0.25 * loss[0] / 33554432.0);
}

// ---------------------------------------------------------------- launcher
extern "C" void kernel_launch(void* const* d_in, const int* in_sizes, int n_in,
                              void* d_out, int out_size, void* d_ws, size_t ws_size,
                              hipStream_t stream) {
  const float* z = (const float*)d_in[0];
  const float* cb = (const float*)d_in[1];
  const float* ema_w = (const float*)d_in[3];

  float* out0 = (float*)d_out;
  float* out1 = out0 + (size_t)N_TOK * D;
  float* out2 = out1 + N_TOK;

  // ws layout, ~2.95 MB total (< proven-safe 3.15 MB)
  char* ws = (char*)d_ws;
  unsigned short* cbb = (unsigned short*)ws;                        // [0, 512K)
  float* dwe = (float*)(ws + 524288);                               // 1 MB
  unsigned long long* small_list = (unsigned long long*)(ws + 1572864);  // 1.375 MB
  int* ovf_list = (int*)(ws + 3014656);                             // 64 KB
  double* inv_nc64 = (double*)(ws + 3080192);                       // 8 KB
  int* small_cnt = (int*)(ws + 3088384);
  int* ovf_cnt = (int*)(ws + 3088388);
  double* loss = (double*)(ws + 3088448);

  hipMemsetAsync(dwe, 0, (size_t)K_CODES * D * sizeof(float), stream);
  hipMemsetAsync(ws + 3088384, 0, 128, stream);  // counters + loss

  norm_cb_kernel<<<K_CODES, 256, 0, stream>>>(cb, inv_nc64, cbb);
  vq_mfma_kernel<<<N_TOK / 32, 512, 0, stream>>>(
      z, (const char*)cbb, dwe, out1, small_list, small_cnt, ovf_list, ovf_cnt);
  recheck_small_kernel<<<2048, 256, 0, stream>>>(
      z, cb, inv_nc64, small_list, small_cnt, out1, dwe);
  fullscan_kernel<<<1024, 256, 0, stream>>>(
      z, cb, inv_nc64, ovf_list, ovf_cnt, out1, dwe);
  ema_embed_kernel<<<K_CODES, 256, 0, stream>>>(ema_w, dwe);
  gather_loss_kernel<<<2048, 256, 0, stream>>>(z, dwe, out1, out0, loss);
  finalize_kernel<<<1, 1, 0, stream>>>(loss, out2);
}